// Round 7
// baseline (384.018 us; speedup 1.0000x reference)
//
#include <hip/hip_runtime.h>

#define NPTS 131072
#define NE 8
#define DIN 90
#define NH 256
#define TILES 2048            // NPTS/64
#define NBLK (NE * TILES)

typedef __attribute__((ext_vector_type(8))) short bf16x8;
typedef __attribute__((ext_vector_type(4))) float f32x4;
typedef __attribute__((ext_vector_type(2))) float f32x2;
typedef __attribute__((ext_vector_type(4))) unsigned int u32x4;
typedef __attribute__((ext_vector_type(2))) unsigned int u32x2;
typedef __attribute__((ext_vector_type(4), aligned(4))) float f32x4a;
typedef __attribute__((ext_vector_type(2), aligned(4))) float f32x2a;

__device__ __forceinline__ unsigned short f2bf(float f) {
  unsigned int u = __float_as_uint(f);
  u += 0x7fffu + ((u >> 16) & 1u);
  return (unsigned short)(u >> 16);
}

#if defined(__has_builtin) && __has_builtin(__builtin_amdgcn_cvt_pk_bf16_f32)
typedef __attribute__((ext_vector_type(2))) __bf16 bf16x2;
__device__ __forceinline__ unsigned int pkbf(float f0, float f1) {
  bf16x2 r = __builtin_amdgcn_cvt_pk_bf16_f32(f0, f1);
  return __builtin_bit_cast(unsigned int, r);
}
#else
__device__ __forceinline__ unsigned int pkbf(float f0, float f1) {
  unsigned int u0 = __float_as_uint(f0) + 0x7fffu;
  unsigned int u1 = __float_as_uint(f1) + 0x7fffu;
  return __builtin_amdgcn_perm(u1, u0, 0x07060302u);
}
#endif

__device__ __forceinline__ bf16x8 cvt8(f32x4 a, f32x4 b) {
  u32x4 r;
  r[0] = pkbf(a[0], a[1]);
  r[1] = pkbf(a[2], a[3]);
  r[2] = pkbf(b[0], b[1]);
  r[3] = pkbf(b[2], b[3]);
  return __builtin_bit_cast(bf16x8, r);
}

// shared by route & expert_gemm -> identical FP sequence -> identical masks
__device__ __forceinline__ void expert_w(const float* __restrict__ cent,
                                         float px, float py, float pz,
                                         float* inv, float* s_out) {
  float dist[NE];
  float mind = 3.4e38f;
#pragma unroll
  for (int e = 0; e < NE; ++e) {
    float dx = px - cent[e * 3 + 0];
    float dy = py - cent[e * 3 + 1];
    float dz = pz - cent[e * 3 + 2];
    float d2 = dx * dx + dy * dy + dz * dz;
    float d = sqrtf(fmaxf(d2, 0.f));
    dist[e] = d;
    mind = fminf(mind, d);
  }
  float s = 0.f;
#pragma unroll
  for (int e = 0; e < NE; ++e) {
    float iv = (dist[e] <= 2.0f * mind) ? 1.f / (dist[e] + 1e-8f) : 0.f;
    inv[e] = iv;
    s += iv;
  }
  *s_out = s;
}

// prep: W1 -> W1T [e][hcol][k96], W2 -> W2T [e][o16][k256] (coalesced reads)
#define PREP_T (184320 + 12288 + 8192 + 24576)
__global__ __launch_bounds__(256) void prep(const float* __restrict__ W1,
                                            const float* __restrict__ W2,
                                            unsigned short* __restrict__ W1T,
                                            unsigned short* __restrict__ W2T) {
  int tid = blockIdx.x * 256 + threadIdx.x;
  if (tid < 184320) {
    float v = W1[tid];
    int n = tid & 255, r = tid >> 8;
    int kp = r % 90, e = r / 90;
    W1T[(size_t)(e * NH + n) * 96 + kp] = f2bf(v);
    return;
  }
  tid -= 184320;
  if (tid < 12288) {
    int kp = 90 + tid % 6, q = tid / 6;
    int n = q & 255, e = q >> 8;
    W1T[(size_t)(e * NH + n) * 96 + kp] = 0;
    return;
  }
  tid -= 12288;
  if (tid < 8192) {
    float v = W2[tid];
    int o = tid & 3, k = (tid >> 2) & 255, e = tid >> 10;
    W2T[(size_t)(e * 16 + o) * NH + k] = f2bf(v);
    return;
  }
  tid -= 8192;
  if (tid < 24576) {
    int k = tid & 255, q = tid >> 8;
    int o = 4 + q % 12, e = q / 12;
    W2T[(size_t)(e * 16 + o) * NH + k] = 0;
  }
}

// route: per point, append n to each active expert's list (ballot-compacted)
__global__ __launch_bounds__(256) void route(const float* __restrict__ x,
                                             const float* __restrict__ cent,
                                             int* __restrict__ cnt,
                                             int* __restrict__ idxList) {
  const int n = blockIdx.x * 256 + threadIdx.x;   // grid exactly covers NPTS
  const int lane = threadIdx.x & 63;
  f32x4 p = *(const f32x4a*)(x + (size_t)n * 93);  // xyz (+1 feat, ignored)
  float inv[NE], s;
  expert_w(cent, p[0], p[1], p[2], inv, &s);
#pragma unroll
  for (int e = 0; e < NE; ++e) {
    bool pred = inv[e] > 0.f;
    unsigned long long m = __ballot(pred);
    if (m) {
      int leader = __ffsll((unsigned long long)m) - 1;
      int base = 0;
      if (lane == leader) base = atomicAdd(&cnt[e], __popcll(m));
      base = __shfl(base, leader, 64);
      if (pred)
        idxList[(size_t)e * NPTS + base + __popcll(m & ((1ull << lane) - 1ull))] = n;
    }
  }
}

// expert_gemm: one (expert, 64-point tile); out += w * (relu(feat@W1+b1)@W2 + b2)
__global__ __launch_bounds__(256, 3) void expert_gemm(
    const float* __restrict__ x, const float* __restrict__ cent,
    const float* __restrict__ b1, const float* __restrict__ b2,
    const unsigned short* __restrict__ W1T, const unsigned short* __restrict__ W2T,
    const int* __restrict__ cnt, const int* __restrict__ idxList,
    float* __restrict__ out) {
  const int e = blockIdx.x >> 11;
  const int tile = blockIdx.x & (TILES - 1);
  const int start = tile * 64;
  const int cn = cnt[e];
  if (start >= cn) return;   // uniform early-exit (no barrier crossed)

  __shared__ unsigned short sH[4 * 2048];  // 16 KB wave-private h (A-frag order)
  __shared__ int sRow[64];
  __shared__ float sWloc[64];

  const int t    = threadIdx.x;
  const int lane = t & 63;
  const int wid  = t >> 6;
  const int l15  = lane & 15;
  const int l4   = lane >> 4;
  const int gbase = wid * 2048;

  // ---- rows + per-point weight for this expert (tail slots: dup row, w=0) ----
  if (t < 64) {
    const int slot = start + t;
    const int sl = (slot < cn) ? slot : start;
    const int n = idxList[(size_t)e * NPTS + sl];
    const float* gx = x + (size_t)n * 93;
    float inv[NE], s;
    expert_w(cent, gx[0], gx[1], gx[2], inv, &s);
    sRow[t] = n;
    sWloc[t] = (slot < cn) ? inv[e] / s : 0.f;
  }
  __syncthreads();

  // ---- gathered feat fragments (B operand), bf16, regs ----
  bf16x8 bfr[4][3];
#pragma unroll
  for (int nf = 0; nf < 4; ++nf) {
    const int n = sRow[16 * nf + l15];
    const float* gr = x + (size_t)n * 93 + 3;
    f32x4 v0, v1;
    v0 = *(const f32x4a*)(gr + 8 * l4);
    v1 = *(const f32x4a*)(gr + 8 * l4 + 4);
    bfr[nf][0] = cvt8(v0, v1);
    v0 = *(const f32x4a*)(gr + 32 + 8 * l4);
    v1 = *(const f32x4a*)(gr + 36 + 8 * l4);
    bfr[nf][1] = cvt8(v0, v1);
    if (l4 < 3) {
      v0 = *(const f32x4a*)(gr + 64 + 8 * l4);
      v1 = *(const f32x4a*)(gr + 68 + 8 * l4);
    } else {
      f32x2 tl = *(const f32x2a*)(gr + 88);
      v0[0] = tl[0]; v0[1] = tl[1]; v0[2] = 0.f; v0[3] = 0.f;
      v1[0] = 0.f; v1[1] = 0.f; v1[2] = 0.f; v1[3] = 0.f;
    }
    bfr[nf][2] = cvt8(v0, v1);
  }

  // ---- 2-chunk loop (64 hcols/wave/chunk), dbuf prefetch as in R6 ----
  bf16x8 w1buf[2][6];
  bf16x8 bwb[2];
  auto loadW1 = [&](int c, int buf) {
    const unsigned short* p =
        W1T + (size_t)(e * NH + 128 * c + 32 * wid + l15) * 96 + 8 * l4;
#pragma unroll
    for (int mf = 0; mf < 2; ++mf)
#pragma unroll
      for (int ks = 0; ks < 3; ++ks)
        w1buf[buf][mf * 3 + ks] = *(const bf16x8*)(p + mf * (16 * 96) + 32 * ks);
  };
  auto loadBW = [&](int c, int buf) {
    bwb[buf] = *(const bf16x8*)(W2T + (size_t)(e * 16 + l15) * NH +
                                128 * c + 32 * wid + 8 * l4);
  };
  loadBW(0, 0);
  loadW1(0, 0);

  // facc C-init: b2 once (wid 0 only; o=l15<4, same for every row)
  const float b2v = (wid == 0 && l15 < 4) ? b2[e * 4 + l15] : 0.f;
  f32x4 facc[4];
#pragma unroll
  for (int rf = 0; rf < 4; ++rf)
#pragma unroll
    for (int r = 0; r < 4; ++r) facc[rf][r] = b2v;

#pragma unroll
  for (int c = 0; c < 2; ++c) {
    if (c == 0) { loadBW(1, 1); loadW1(1, 1); }   // prefetch chunk 1
    const int colbase = 128 * c + 32 * wid;
    f32x4 b1v0 = *(const f32x4a*)(b1 + e * NH + colbase + 4 * l4);
    f32x4 b1v1 = *(const f32x4a*)(b1 + e * NH + colbase + 16 + 4 * l4);

#pragma unroll
    for (int mf = 0; mf < 2; ++mf) {
      const f32x4 b1v = (mf == 0) ? b1v0 : b1v1;
      f32x4 acc[4];
#pragma unroll
      for (int nf = 0; nf < 4; ++nf)
        acc[nf] = __builtin_amdgcn_mfma_f32_16x16x32_bf16(
            w1buf[c][mf * 3 + 0], bfr[nf][0], b1v, 0, 0, 0);
#pragma unroll
      for (int ks = 1; ks < 3; ++ks)
#pragma unroll
        for (int nf = 0; nf < 4; ++nf)
          acc[nf] = __builtin_amdgcn_mfma_f32_16x16x32_bf16(
              w1buf[c][mf * 3 + ks], bfr[nf][ks], acc[nf], 0, 0, 0);

      // epilogue: relu + pack only (w factored out of layer 2)
#pragma unroll
      for (int nf = 0; nf < 4; ++nf) {
        f32x4 a = acc[nf];
        u32x2 pk;
        pk[0] = pkbf(fmaxf(a[0], 0.f), fmaxf(a[1], 0.f));
        pk[1] = pkbf(fmaxf(a[2], 0.f), fmaxf(a[3], 0.f));
        *(u32x2*)&sH[gbase + (nf * 64 + (l15 + 16 * (2 * mf + (l4 >> 1)))) * 8 +
                     4 * (l4 & 1)] = pk;
      }
    }

    // layer 2 (wave-private sH round-trip)
#pragma unroll
    for (int rf = 0; rf < 4; ++rf) {
      bf16x8 ah = *(const bf16x8*)&sH[gbase + (rf * 64 + lane) * 8];
      facc[rf] = __builtin_amdgcn_mfma_f32_16x16x32_bf16(ah, bwb[c], facc[rf], 0, 0, 0);
    }
  }

  // ---- scale by w (per row), cross-wave reduce, atomic accumulate ----
#pragma unroll
  for (int rf = 0; rf < 4; ++rf)
#pragma unroll
    for (int r = 0; r < 4; ++r)
      facc[rf][r] *= sWloc[16 * rf + 4 * l4 + r];

  __syncthreads();
  float* sOutP = (float*)sH;   // 4 KB of the 16 KB region
  if (l15 < 4) {
#pragma unroll
    for (int rf = 0; rf < 4; ++rf)
#pragma unroll
      for (int r = 0; r < 4; ++r)
        sOutP[(wid * 64 + 16 * rf + 4 * l4 + r) * 4 + l15] = facc[rf][r];
  }
  __syncthreads();
  {
    const int row = t >> 2, o = t & 3;
    float v = sOutP[(0 * 64 + row) * 4 + o] + sOutP[(1 * 64 + row) * 4 + o] +
              sOutP[(2 * 64 + row) * 4 + o] + sOutP[(3 * 64 + row) * 4 + o];
    atomicAdd(&out[(size_t)sRow[row] * 4 + o], v);
  }
}

extern "C" void kernel_launch(void* const* d_in, const int* in_sizes, int n_in,
                              void* d_out, int out_size, void* d_ws, size_t ws_size,
                              hipStream_t stream) {
  const float* x    = (const float*)d_in[0];
  const float* cent = (const float*)d_in[1];
  const float* W1   = (const float*)d_in[2];
  const float* b1   = (const float*)d_in[3];
  const float* W2   = (const float*)d_in[4];
  const float* b2   = (const float*)d_in[5];
  float* out = (float*)d_out;

  // ws layout: W1T 393216 | W2T 65536 | cnt 64 | idxList 4194304  (~4.66 MB)
  unsigned short* W1T = (unsigned short*)d_ws;
  unsigned short* W2T = W1T + NE * NH * 96;
  int* cnt     = (int*)((char*)d_ws + 458752);
  int* idxList = (int*)((char*)d_ws + 458816);

  hipMemsetAsync(cnt, 0, 64, stream);
  hipMemsetAsync(out, 0, (size_t)NPTS * 4 * sizeof(float), stream);
  prep<<<(PREP_T + 255) / 256, 256, 0, stream>>>(W1, W2, W1T, W2T);
  route<<<NPTS / 256, 256, 0, stream>>>(x, cent, cnt, idxList);
  expert_gemm<<<NBLK, 256, 0, stream>>>(x, cent, b1, b2, W1T, W2T, cnt, idxList, out);
}

// Round 8
// 207.253 us; speedup vs baseline: 1.8529x; 1.8529x over previous
//
#include <hip/hip_runtime.h>

#define NPTS 131072
#define NE 8
#define DIN 90
#define NH 256
#define TILES 2048            // NPTS/64
#define NBLK (NE * TILES)
#define RBLK 512              // NPTS/256 route-phase blocks

typedef __attribute__((ext_vector_type(8))) short bf16x8;
typedef __attribute__((ext_vector_type(4))) float f32x4;
typedef __attribute__((ext_vector_type(2))) float f32x2;
typedef __attribute__((ext_vector_type(4))) unsigned int u32x4;
typedef __attribute__((ext_vector_type(2))) unsigned int u32x2;
typedef __attribute__((ext_vector_type(2))) int i32x2;
typedef __attribute__((ext_vector_type(4))) int i32x4;
typedef __attribute__((ext_vector_type(4), aligned(4))) float f32x4a;
typedef __attribute__((ext_vector_type(2), aligned(4))) float f32x2a;

__device__ __forceinline__ unsigned short f2bf(float f) {
  unsigned int u = __float_as_uint(f);
  u += 0x7fffu + ((u >> 16) & 1u);
  return (unsigned short)(u >> 16);
}

#if defined(__has_builtin) && __has_builtin(__builtin_amdgcn_cvt_pk_bf16_f32)
typedef __attribute__((ext_vector_type(2))) __bf16 bf16x2;
__device__ __forceinline__ unsigned int pkbf(float f0, float f1) {
  bf16x2 r = __builtin_amdgcn_cvt_pk_bf16_f32(f0, f1);
  return __builtin_bit_cast(unsigned int, r);
}
#else
__device__ __forceinline__ unsigned int pkbf(float f0, float f1) {
  unsigned int u0 = __float_as_uint(f0) + 0x7fffu;
  unsigned int u1 = __float_as_uint(f1) + 0x7fffu;
  return __builtin_amdgcn_perm(u1, u0, 0x07060302u);
}
#endif

__device__ __forceinline__ bf16x8 cvt8(f32x4 a, f32x4 b) {
  u32x4 r;
  r[0] = pkbf(a[0], a[1]);
  r[1] = pkbf(a[2], a[3]);
  r[2] = pkbf(b[0], b[1]);
  r[3] = pkbf(b[2], b[3]);
  return __builtin_bit_cast(bf16x8, r);
}

// identical FP sequence everywhere -> identical masks
__device__ __forceinline__ void expert_w(const float* __restrict__ cent,
                                         float px, float py, float pz,
                                         float* inv, float* s_out) {
  float dist[NE];
  float mind = 3.4e38f;
#pragma unroll
  for (int e = 0; e < NE; ++e) {
    float dx = px - cent[e * 3 + 0];
    float dy = py - cent[e * 3 + 1];
    float dz = pz - cent[e * 3 + 2];
    float d2 = dx * dx + dy * dy + dz * dz;
    float d = sqrtf(fmaxf(d2, 0.f));
    dist[e] = d;
    mind = fminf(mind, d);
  }
  float s = 0.f;
#pragma unroll
  for (int e = 0; e < NE; ++e) {
    float iv = (dist[e] <= 2.0f * mind) ? 1.f / (dist[e] + 1e-8f) : 0.f;
    inv[e] = iv;
    s += iv;
  }
  *s_out = s;
}

// ---- prep: W1 -> W1T [e][hcol][k96], W2 -> W2T [e][o16][k256] ----
#define PREP_T (184320 + 12288 + 8192 + 24576)
__global__ __launch_bounds__(256) void prep(const float* __restrict__ W1,
                                            const float* __restrict__ W2,
                                            unsigned short* __restrict__ W1T,
                                            unsigned short* __restrict__ W2T) {
  int tid = blockIdx.x * 256 + threadIdx.x;
  if (tid < 184320) {
    float v = W1[tid];
    int n = tid & 255, r = tid >> 8;
    int kp = r % 90, e = r / 90;
    W1T[(size_t)(e * NH + n) * 96 + kp] = f2bf(v);
    return;
  }
  tid -= 184320;
  if (tid < 12288) {
    int kp = 90 + tid % 6, q = tid / 6;
    int n = q & 255, e = q >> 8;
    W1T[(size_t)(e * NH + n) * 96 + kp] = 0;
    return;
  }
  tid -= 12288;
  if (tid < 8192) {
    float v = W2[tid];
    int o = tid & 3, k = (tid >> 2) & 255, e = tid >> 10;
    W2T[(size_t)(e * 16 + o) * NH + k] = f2bf(v);
    return;
  }
  tid -= 8192;
  if (tid < 24576) {
    int k = tid & 255, q = tid >> 8;
    int o = 4 + q % 12, e = q / 12;
    W2T[(size_t)(e * 16 + o) * NH + k] = 0;
  }
}

// ---- phase 1: per-block active counts (NO global atomics) ----
__global__ __launch_bounds__(256) void route_count(const float* __restrict__ x,
                                                   const float* __restrict__ cent,
                                                   int* __restrict__ blkcnt) {
  __shared__ int wcnt[NE][4];
  const int b = blockIdx.x, t = threadIdx.x;
  const int lane = t & 63, wid = t >> 6;
  const int n = b * 256 + t;
  f32x4 p = *(const f32x4a*)(x + (size_t)n * 93);
  float inv[NE], s;
  expert_w(cent, p[0], p[1], p[2], inv, &s);
#pragma unroll
  for (int e = 0; e < NE; ++e) {
    unsigned long long m = __ballot(inv[e] > 0.f);
    if (lane == 0) wcnt[e][wid] = __popcll(m);
  }
  __syncthreads();
  if (t < NE)
    blkcnt[t * RBLK + b] = wcnt[t][0] + wcnt[t][1] + wcnt[t][2] + wcnt[t][3];
}

// ---- phase 2: exclusive scan per expert (single block, 512 threads) ----
__global__ __launch_bounds__(512) void route_scan(const int* __restrict__ blkcnt,
                                                  int* __restrict__ base,
                                                  int* __restrict__ cnt) {
  __shared__ int s[RBLK];
  const int t = threadIdx.x;
  for (int e = 0; e < NE; ++e) {
    const int v = blkcnt[e * RBLK + t];
    s[t] = v;
    __syncthreads();
    for (int off = 1; off < RBLK; off <<= 1) {
      int a = (t >= off) ? s[t - off] : 0;
      __syncthreads();
      s[t] += a;
      __syncthreads();
    }
    base[e * RBLK + t] = s[t] - v;   // exclusive
    if (t == RBLK - 1) cnt[e] = s[t];
    __syncthreads();
  }
}

// ---- phase 3: scatter {idx, w} into per-expert segments + posList ----
__global__ __launch_bounds__(256) void route_scatter(const float* __restrict__ x,
                                                     const float* __restrict__ cent,
                                                     const int* __restrict__ base,
                                                     i32x2* __restrict__ idxw,
                                                     int* __restrict__ posList) {
  __shared__ int wcnt[NE][4];
  const int b = blockIdx.x, t = threadIdx.x;
  const int lane = t & 63, wid = t >> 6;
  const int n = b * 256 + t;
  f32x4 p = *(const f32x4a*)(x + (size_t)n * 93);
  float inv[NE], s;
  expert_w(cent, p[0], p[1], p[2], inv, &s);
  const float rs = 1.f / s;
  unsigned long long m[NE];
#pragma unroll
  for (int e = 0; e < NE; ++e) {
    m[e] = __ballot(inv[e] > 0.f);
    if (lane == 0) wcnt[e][wid] = __popcll(m[e]);
  }
  __syncthreads();
  const unsigned long long ltmask = (1ull << lane) - 1ull;
#pragma unroll
  for (int e = 0; e < NE; ++e) {
    int pos = -1;
    if (inv[e] > 0.f) {
      int off = base[e * RBLK + b];
      for (int w = 0; w < 4; ++w)
        if (w < wid) off += wcnt[e][w];
      off += __popcll(m[e] & ltmask);
      i32x2 rec;
      rec[0] = n;
      rec[1] = __float_as_int(inv[e] * rs);
      idxw[(size_t)e * NPTS + off] = rec;
      pos = off;
    }
    posList[(size_t)n * NE + e] = pos;
  }
}

// ---- expert gemm: yList[e][slot] = w * (relu(feat@W1+b1)@W2 + b2), coalesced ----
__global__ __launch_bounds__(256, 3) void expert_gemm(
    const float* __restrict__ x,
    const float* __restrict__ b1, const float* __restrict__ b2,
    const unsigned short* __restrict__ W1T, const unsigned short* __restrict__ W2T,
    const int* __restrict__ cnt, const i32x2* __restrict__ idxw,
    float* __restrict__ yList) {
  const int e = blockIdx.x >> 11;
  const int start = (blockIdx.x & (TILES - 1)) * 64;
  const int cn = cnt[e];
  if (start >= cn) return;

  __shared__ unsigned short sH[4 * 2048];  // 16 KB wave-private h (A-frag order)
  __shared__ int sRow[64];
  __shared__ float sWloc[64];

  const int t    = threadIdx.x;
  const int lane = t & 63;
  const int wid  = t >> 6;
  const int l15  = lane & 15;
  const int l4   = lane >> 4;
  const int gbase = wid * 2048;

  if (t < 64) {
    const int slot = start + t;
    i32x2 rec = idxw[(size_t)e * NPTS + ((slot < cn) ? slot : start)];
    sRow[t] = rec[0];
    sWloc[t] = (slot < cn) ? __int_as_float(rec[1]) : 0.f;
  }
  __syncthreads();

  // gathered feat fragments (B operand), bf16, regs
  bf16x8 bfr[4][3];
#pragma unroll
  for (int nf = 0; nf < 4; ++nf) {
    const int n = sRow[16 * nf + l15];
    const float* gr = x + (size_t)n * 93 + 3;
    f32x4 v0, v1;
    v0 = *(const f32x4a*)(gr + 8 * l4);
    v1 = *(const f32x4a*)(gr + 8 * l4 + 4);
    bfr[nf][0] = cvt8(v0, v1);
    v0 = *(const f32x4a*)(gr + 32 + 8 * l4);
    v1 = *(const f32x4a*)(gr + 36 + 8 * l4);
    bfr[nf][1] = cvt8(v0, v1);
    if (l4 < 3) {
      v0 = *(const f32x4a*)(gr + 64 + 8 * l4);
      v1 = *(const f32x4a*)(gr + 68 + 8 * l4);
    } else {
      f32x2 tl = *(const f32x2a*)(gr + 88);
      v0[0] = tl[0]; v0[1] = tl[1]; v0[2] = 0.f; v0[3] = 0.f;
      v1[0] = 0.f; v1[1] = 0.f; v1[2] = 0.f; v1[3] = 0.f;
    }
    bfr[nf][2] = cvt8(v0, v1);
  }

  bf16x8 w1buf[2][6];
  bf16x8 bwb[2];
  auto loadW1 = [&](int c, int buf) {
    const unsigned short* p =
        W1T + (size_t)(e * NH + 128 * c + 32 * wid + l15) * 96 + 8 * l4;
#pragma unroll
    for (int mf = 0; mf < 2; ++mf)
#pragma unroll
      for (int ks = 0; ks < 3; ++ks)
        w1buf[buf][mf * 3 + ks] = *(const bf16x8*)(p + mf * (16 * 96) + 32 * ks);
  };
  auto loadBW = [&](int c, int buf) {
    bwb[buf] = *(const bf16x8*)(W2T + (size_t)(e * 16 + l15) * NH +
                                128 * c + 32 * wid + 8 * l4);
  };
  loadBW(0, 0);
  loadW1(0, 0);

  const float b2v = (wid == 0 && l15 < 4) ? b2[e * 4 + l15] : 0.f;
  f32x4 facc[4];
#pragma unroll
  for (int rf = 0; rf < 4; ++rf)
#pragma unroll
    for (int r = 0; r < 4; ++r) facc[rf][r] = b2v;

#pragma unroll
  for (int c = 0; c < 2; ++c) {
    if (c == 0) { loadBW(1, 1); loadW1(1, 1); }
    const int colbase = 128 * c + 32 * wid;
    f32x4 b1v0 = *(const f32x4a*)(b1 + e * NH + colbase + 4 * l4);
    f32x4 b1v1 = *(const f32x4a*)(b1 + e * NH + colbase + 16 + 4 * l4);

#pragma unroll
    for (int mf = 0; mf < 2; ++mf) {
      const f32x4 b1v = (mf == 0) ? b1v0 : b1v1;
      f32x4 acc[4];
#pragma unroll
      for (int nf = 0; nf < 4; ++nf)
        acc[nf] = __builtin_amdgcn_mfma_f32_16x16x32_bf16(
            w1buf[c][mf * 3 + 0], bfr[nf][0], b1v, 0, 0, 0);
#pragma unroll
      for (int ks = 1; ks < 3; ++ks)
#pragma unroll
        for (int nf = 0; nf < 4; ++nf)
          acc[nf] = __builtin_amdgcn_mfma_f32_16x16x32_bf16(
              w1buf[c][mf * 3 + ks], bfr[nf][ks], acc[nf], 0, 0, 0);

#pragma unroll
      for (int nf = 0; nf < 4; ++nf) {
        f32x4 a = acc[nf];
        u32x2 pk;
        pk[0] = pkbf(fmaxf(a[0], 0.f), fmaxf(a[1], 0.f));
        pk[1] = pkbf(fmaxf(a[2], 0.f), fmaxf(a[3], 0.f));
        *(u32x2*)&sH[gbase + (nf * 64 + (l15 + 16 * (2 * mf + (l4 >> 1)))) * 8 +
                     4 * (l4 & 1)] = pk;
      }
    }

#pragma unroll
    for (int rf = 0; rf < 4; ++rf) {
      bf16x8 ah = *(const bf16x8*)&sH[gbase + (rf * 64 + lane) * 8];
      facc[rf] = __builtin_amdgcn_mfma_f32_16x16x32_bf16(ah, bwb[c], facc[rf], 0, 0, 0);
    }
  }

  // scale by w, cross-wave reduce, COALESCED store (no atomics)
#pragma unroll
  for (int rf = 0; rf < 4; ++rf)
#pragma unroll
    for (int r = 0; r < 4; ++r)
      facc[rf][r] *= sWloc[16 * rf + 4 * l4 + r];

  __syncthreads();
  float* sOutP = (float*)sH;
  if (l15 < 4) {
#pragma unroll
    for (int rf = 0; rf < 4; ++rf)
#pragma unroll
      for (int r = 0; r < 4; ++r)
        sOutP[(wid * 64 + 16 * rf + 4 * l4 + r) * 4 + l15] = facc[rf][r];
  }
  __syncthreads();
  {
    const int row = t >> 2, o = t & 3;
    float v = sOutP[(0 * 64 + row) * 4 + o] + sOutP[(1 * 64 + row) * 4 + o] +
              sOutP[(2 * 64 + row) * 4 + o] + sOutP[(3 * 64 + row) * 4 + o];
    yList[((size_t)e * NPTS + start + row) * 4 + o] = v;
  }
}

// ---- combine: out[n] = sum_e yList[e][pos[n][e]]  (regular loads, no atomics) ----
__global__ __launch_bounds__(256) void combine(const int* __restrict__ posList,
                                               const float* __restrict__ yList,
                                               float* __restrict__ out) {
  const int n = blockIdx.x * 256 + threadIdx.x;
  i32x4 p0 = *(const i32x4*)(posList + (size_t)n * NE);
  i32x4 p1 = *(const i32x4*)(posList + (size_t)n * NE + 4);
  f32x4 acc = {0.f, 0.f, 0.f, 0.f};
#pragma unroll
  for (int j = 0; j < 4; ++j) {
    if (p0[j] >= 0) acc += *(const f32x4*)(yList + ((size_t)j * NPTS + p0[j]) * 4);
    if (p1[j] >= 0) acc += *(const f32x4*)(yList + ((size_t)(j + 4) * NPTS + p1[j]) * 4);
  }
  *(f32x4*)(out + (size_t)n * 4) = acc;
}

extern "C" void kernel_launch(void* const* d_in, const int* in_sizes, int n_in,
                              void* d_out, int out_size, void* d_ws, size_t ws_size,
                              hipStream_t stream) {
  const float* x    = (const float*)d_in[0];
  const float* cent = (const float*)d_in[1];
  const float* W1   = (const float*)d_in[2];
  const float* b1   = (const float*)d_in[3];
  const float* W2   = (const float*)d_in[4];
  const float* b2   = (const float*)d_in[5];
  float* out = (float*)d_out;

  // ws layout (64B-aligned offsets), total ~28.5 MB
  char* w = (char*)d_ws;
  unsigned short* W1T = (unsigned short*)(w + 0);        // 393216
  unsigned short* W2T = (unsigned short*)(w + 393216);   // 65536
  int* cnt     = (int*)(w + 458752);                     // 32 (+pad)
  int* blkcnt  = (int*)(w + 458816);                     // 16384
  int* base    = (int*)(w + 475200);                     // 16384
  i32x2* idxw  = (i32x2*)(w + 491584);                   // 8388608
  int* posList = (int*)(w + 8880192);                    // 4194304
  float* yList = (float*)(w + 13074496);                 // 16777216

  prep<<<(PREP_T + 255) / 256, 256, 0, stream>>>(W1, W2, W1T, W2T);
  route_count<<<RBLK, 256, 0, stream>>>(x, cent, blkcnt);
  route_scan<<<1, 512, 0, stream>>>(blkcnt, base, cnt);
  route_scatter<<<RBLK, 256, 0, stream>>>(x, cent, base, idxw, posList);
  expert_gemm<<<NBLK, 256, 0, stream>>>(x, b1, b2, W1T, W2T, cnt, idxw, yList);
  combine<<<NPTS / 256, 256, 0, stream>>>(posList, yList, out);
}

// Round 9
// 173.048 us; speedup vs baseline: 2.2191x; 1.1977x over previous
//
#include <hip/hip_runtime.h>

#define NPTS 131072
#define NE 8
#define DIN 90
#define NH 256

typedef __attribute__((ext_vector_type(8))) short bf16x8;
typedef __attribute__((ext_vector_type(4))) float f32x4;
typedef __attribute__((ext_vector_type(2))) float f32x2;
typedef __attribute__((ext_vector_type(4))) unsigned int u32x4;
typedef __attribute__((ext_vector_type(2))) unsigned int u32x2;
typedef __attribute__((ext_vector_type(4), aligned(4))) float f32x4a;
typedef __attribute__((ext_vector_type(2), aligned(4))) float f32x2a;

__device__ __forceinline__ unsigned short f2bf(float f) {
  unsigned int u = __float_as_uint(f);
  u += 0x7fffu + ((u >> 16) & 1u);
  return (unsigned short)(u >> 16);
}

#if defined(__has_builtin) && __has_builtin(__builtin_amdgcn_cvt_pk_bf16_f32)
typedef __attribute__((ext_vector_type(2))) __bf16 bf16x2;
__device__ __forceinline__ unsigned int pkbf(float f0, float f1) {
  bf16x2 r = __builtin_amdgcn_cvt_pk_bf16_f32(f0, f1);
  return __builtin_bit_cast(unsigned int, r);
}
#else
__device__ __forceinline__ unsigned int pkbf(float f0, float f1) {
  unsigned int u0 = __float_as_uint(f0) + 0x7fffu;
  unsigned int u1 = __float_as_uint(f1) + 0x7fffu;
  return __builtin_amdgcn_perm(u1, u0, 0x07060302u);
}
#endif

__device__ __forceinline__ bf16x8 cvt8(f32x4 a, f32x4 b) {
  u32x4 r;
  r[0] = pkbf(a[0], a[1]);
  r[1] = pkbf(a[2], a[3]);
  r[2] = pkbf(b[0], b[1]);
  r[3] = pkbf(b[2], b[3]);
  return __builtin_bit_cast(bf16x8, r);
}

// prep: W1 -> W1T [e][hcol][k96], W2 -> W2T [e][o16][k256]
#define PREP_T (184320 + 12288 + 8192 + 24576)
__global__ __launch_bounds__(256) void prep(const float* __restrict__ W1,
                                            const float* __restrict__ W2,
                                            unsigned short* __restrict__ W1T,
                                            unsigned short* __restrict__ W2T) {
  int tid = blockIdx.x * 256 + threadIdx.x;
  if (tid < 184320) {
    float v = W1[tid];
    int n = tid & 255, r = tid >> 8;
    int kp = r % 90, e = r / 90;
    W1T[(size_t)(e * NH + n) * 96 + kp] = f2bf(v);
    return;
  }
  tid -= 184320;
  if (tid < 12288) {
    int kp = 90 + tid % 6, q = tid / 6;
    int n = q & 255, e = q >> 8;
    W1T[(size_t)(e * NH + n) * 96 + kp] = 0;
    return;
  }
  tid -= 12288;
  if (tid < 8192) {
    float v = W2[tid];
    int o = tid & 3, k = (tid >> 2) & 255, e = tid >> 10;
    W2T[(size_t)(e * 16 + o) * NH + k] = f2bf(v);
    return;
  }
  tid -= 8192;
  if (tid < 24576) {
    int k = tid & 255, q = tid >> 8;
    int o = 4 + q % 12, e = q / 12;
    W2T[(size_t)(e * 16 + o) * NH + k] = 0;
  }
}

// Chunk-delayed layer-2 pipeline: iter i writes h->region(i&1), runs layer-2 on
// region((i-1)&1). The ds_read latency hides behind 24 layer-1 MFMAs instead of
// sitting on the write->read critical path.
__global__ __launch_bounds__(256, 3) void meganerf_main(
    const float* __restrict__ x, const float* __restrict__ cent,
    const float* __restrict__ b1, const float* __restrict__ b2,
    const unsigned short* __restrict__ W1T, const unsigned short* __restrict__ W2T,
    float* __restrict__ out) {
  __shared__ unsigned short sH[8 * 4096];  // 32768 B: 2 regions x 4KB per wave
  __shared__ float sW[NE][64];             // 2048 B
  __shared__ float sB2[64][4];             // 1024 B  -> 35840 B total (4 blocks/CU)

  const int t    = threadIdx.x;
  const int lane = t & 63;
  const int wid  = t >> 6;
  const int l15  = lane & 15;
  const int l4   = lane >> 4;
  const int row0 = blockIdx.x * 64;
  const int gbase = wid * 4096;   // shorts; +2048 per region

  // ---- feat fragments (MFMA B operand), regs for all experts ----
  bf16x8 bfr[4][3];
#pragma unroll
  for (int nf = 0; nf < 4; ++nf) {
    const float* gr = x + (size_t)(row0 + 16 * nf + l15) * 93 + 3;
    f32x4 v0, v1;
    v0 = *(const f32x4a*)(gr + 8 * l4);
    v1 = *(const f32x4a*)(gr + 8 * l4 + 4);
    bfr[nf][0] = cvt8(v0, v1);
    v0 = *(const f32x4a*)(gr + 32 + 8 * l4);
    v1 = *(const f32x4a*)(gr + 36 + 8 * l4);
    bfr[nf][1] = cvt8(v0, v1);
    if (l4 < 3) {
      v0 = *(const f32x4a*)(gr + 64 + 8 * l4);
      v1 = *(const f32x4a*)(gr + 68 + 8 * l4);
    } else {
      f32x2 tl = *(const f32x2a*)(gr + 88);
      v0[0] = tl[0]; v0[1] = tl[1]; v0[2] = 0.f; v0[3] = 0.f;
      v1[0] = 0.f; v1[1] = 0.f; v1[2] = 0.f; v1[3] = 0.f;
    }
    bfr[nf][2] = cvt8(v0, v1);
  }

  // ---- per-point expert weights ----
  if (t < 64) {
    const float* gx = x + (size_t)(row0 + t) * 93;
    float px = gx[0], py = gx[1], pz = gx[2];
    float dist[NE], inv[NE];
    float mind = 3.4e38f;
#pragma unroll
    for (int e = 0; e < NE; ++e) {
      float dx = px - cent[e * 3 + 0];
      float dy = py - cent[e * 3 + 1];
      float dz = pz - cent[e * 3 + 2];
      float d2 = dx * dx + dy * dy + dz * dz;
      float d = sqrtf(fmaxf(d2, 0.f));
      dist[e] = d;
      inv[e] = 1.f / (d + 1e-8f);
      mind = fminf(mind, d);
    }
    float s = 0.f;
#pragma unroll
    for (int e = 0; e < NE; ++e) {
      if (dist[e] > 2.0f * mind) inv[e] = 0.f;
      s += inv[e];
    }
    float rs = 1.f / s;
    float bb[4] = {0.f, 0.f, 0.f, 0.f};
#pragma unroll
    for (int e = 0; e < NE; ++e) {
      float w = inv[e] * rs;
      sW[e][t] = w;
#pragma unroll
      for (int o = 0; o < 4; ++o) bb[o] += w * b2[e * 4 + o];
    }
#pragma unroll
    for (int o = 0; o < 4; ++o) sB2[t][o] = bb[o];
  }
  __syncthreads();   // covers sW, sB2

  f32x4 facc[4] = {{0.f, 0.f, 0.f, 0.f}, {0.f, 0.f, 0.f, 0.f},
                   {0.f, 0.f, 0.f, 0.f}, {0.f, 0.f, 0.f, 0.f}};
  float wv[4];

#pragma unroll 2
  for (int i = 0; i < 16; ++i) {
    const int e = i >> 1, c = i & 1;
    const int cur = i & 1, prev = cur ^ 1;
    const int colbase = 128 * c + 32 * wid;

    // ---- layer-2 for PREVIOUS chunk: issue reads early, compute later ----
    bf16x8 ah[4];
    bf16x8 bwp;
    if (i > 0) {
      const int ep = (i - 1) >> 1, cp = (i - 1) & 1;
#pragma unroll
      for (int rf = 0; rf < 4; ++rf)
        ah[rf] = *(const bf16x8*)&sH[gbase + prev * 2048 + (rf * 64 + lane) * 8];
      bwp = *(const bf16x8*)(W2T + (size_t)(ep * 16 + l15) * NH +
                             128 * cp + 32 * wid + 8 * l4);
    }

    // ---- this chunk's operands ----
    f32x4 b1v0 = *(const f32x4a*)(b1 + e * NH + colbase + 4 * l4);
    f32x4 b1v1 = *(const f32x4a*)(b1 + e * NH + colbase + 16 + 4 * l4);
    bf16x8 w1f[6];
    {
      const unsigned short* p =
          W1T + (size_t)(e * NH + colbase + l15) * 96 + 8 * l4;
#pragma unroll
      for (int mf = 0; mf < 2; ++mf)
#pragma unroll
        for (int ks = 0; ks < 3; ++ks)
          w1f[mf * 3 + ks] = *(const bf16x8*)(p + mf * (16 * 96) + 32 * ks);
    }
    if (c == 0) {
#pragma unroll
      for (int nf = 0; nf < 4; ++nf) wv[nf] = sW[e][16 * nf + l15];
    }

    // ---- layer 1, mf-sequential ----
#pragma unroll
    for (int mf = 0; mf < 2; ++mf) {
      const f32x4 b1v = (mf == 0) ? b1v0 : b1v1;
      f32x4 acc[4];
#pragma unroll
      for (int nf = 0; nf < 4; ++nf)
        acc[nf] = __builtin_amdgcn_mfma_f32_16x16x32_bf16(
            w1f[mf * 3 + 0], bfr[nf][0], b1v, 0, 0, 0);
#pragma unroll
      for (int ks = 1; ks < 3; ++ks)
#pragma unroll
        for (int nf = 0; nf < 4; ++nf)
          acc[nf] = __builtin_amdgcn_mfma_f32_16x16x32_bf16(
              w1f[mf * 3 + ks], bfr[nf][ks], acc[nf], 0, 0, 0);

      // layer-2 MFMAs for prev chunk between the two mf groups (reads long done)
      if (mf == 0 && i > 0) {
#pragma unroll
        for (int rf = 0; rf < 4; ++rf)
          facc[rf] = __builtin_amdgcn_mfma_f32_16x16x32_bf16(ah[rf], bwp, facc[rf], 0, 0, 0);
      }

      // epilogue: relu*w, pack, write region `cur`
#pragma unroll
      for (int nf = 0; nf < 4; ++nf) {
        const float w = wv[nf];
        f32x4 a = acc[nf];
        f32x2 p0, p1;
        p0[0] = a[0]; p0[1] = a[1];
        p1[0] = a[2]; p1[1] = a[3];
        const f32x2 z = {0.f, 0.f};
        p0 = __builtin_elementwise_max(p0, z) * w;
        p1 = __builtin_elementwise_max(p1, z) * w;
        u32x2 pk;
        pk[0] = pkbf(p0[0], p0[1]);
        pk[1] = pkbf(p1[0], p1[1]);
        *(u32x2*)&sH[gbase + cur * 2048 +
                     (nf * 64 + (l15 + 16 * (2 * mf + (l4 >> 1)))) * 8 +
                     4 * (l4 & 1)] = pk;
      }
    }
  }

  // ---- drain: layer-2 for chunk 15 (region 1, expert 7, c=1) ----
  {
    bf16x8 bwp = *(const bf16x8*)(W2T + (size_t)(7 * 16 + l15) * NH +
                                  128 + 32 * wid + 8 * l4);
#pragma unroll
    for (int rf = 0; rf < 4; ++rf) {
      bf16x8 ah = *(const bf16x8*)&sH[gbase + 2048 + (rf * 64 + lane) * 8];
      facc[rf] = __builtin_amdgcn_mfma_f32_16x16x32_bf16(ah, bwp, facc[rf], 0, 0, 0);
    }
  }

  // ---- cross-wave reduction (sOutP aliased onto sH) ----
  __syncthreads();
  float* sOutP = (float*)sH;
  if (l15 < 4) {
#pragma unroll
    for (int rf = 0; rf < 4; ++rf)
#pragma unroll
      for (int r = 0; r < 4; ++r)
        sOutP[(wid * 64 + 16 * rf + 4 * l4 + r) * 4 + l15] = facc[rf][r];
  }
  __syncthreads();
  {
    const int row = t >> 2, o = t & 3;
    float v = sB2[row][o] + sOutP[(0 * 64 + row) * 4 + o] + sOutP[(1 * 64 + row) * 4 + o] +
              sOutP[(2 * 64 + row) * 4 + o] + sOutP[(3 * 64 + row) * 4 + o];
    out[row0 * 4 + t] = v;
  }
}

extern "C" void kernel_launch(void* const* d_in, const int* in_sizes, int n_in,
                              void* d_out, int out_size, void* d_ws, size_t ws_size,
                              hipStream_t stream) {
  const float* x    = (const float*)d_in[0];
  const float* cent = (const float*)d_in[1];
  const float* W1   = (const float*)d_in[2];
  const float* b1   = (const float*)d_in[3];
  const float* W2   = (const float*)d_in[4];
  const float* b2   = (const float*)d_in[5];
  float* out = (float*)d_out;

  unsigned short* W1T = (unsigned short*)d_ws;   // 393216 B
  unsigned short* W2T = W1T + NE * NH * 96;      // 65536 B

  prep<<<(PREP_T + 255) / 256, 256, 0, stream>>>(W1, W2, W1T, W2T);
  meganerf_main<<<NPTS / 64, 256, 0, stream>>>(x, cent, b1, b2, W1T, W2T, out);
}

// Round 10
// 166.103 us; speedup vs baseline: 2.3119x; 1.0418x over previous
//
#include <hip/hip_runtime.h>

#define NPTS 131072
#define NE 8
#define DIN 90
#define NH 256

typedef __attribute__((ext_vector_type(8))) short bf16x8;
typedef __attribute__((ext_vector_type(4))) float f32x4;
typedef __attribute__((ext_vector_type(2))) float f32x2;
typedef __attribute__((ext_vector_type(4))) unsigned int u32x4;
typedef __attribute__((ext_vector_type(2))) unsigned int u32x2;
typedef __attribute__((ext_vector_type(4), aligned(4))) float f32x4a;
typedef __attribute__((ext_vector_type(2), aligned(4))) float f32x2a;

__device__ __forceinline__ unsigned short f2bf(float f) {
  unsigned int u = __float_as_uint(f);
  u += 0x7fffu + ((u >> 16) & 1u);
  return (unsigned short)(u >> 16);
}

#if defined(__has_builtin) && __has_builtin(__builtin_amdgcn_cvt_pk_bf16_f32)
typedef __attribute__((ext_vector_type(2))) __bf16 bf16x2;
__device__ __forceinline__ unsigned int pkbf(float f0, float f1) {
  bf16x2 r = __builtin_amdgcn_cvt_pk_bf16_f32(f0, f1);
  return __builtin_bit_cast(unsigned int, r);
}
#else
__device__ __forceinline__ unsigned int pkbf(float f0, float f1) {
  unsigned int u0 = __float_as_uint(f0) + 0x7fffu;
  unsigned int u1 = __float_as_uint(f1) + 0x7fffu;
  return __builtin_amdgcn_perm(u1, u0, 0x07060302u);
}
#endif

__device__ __forceinline__ bf16x8 cvt8(f32x4 a, f32x4 b) {
  u32x4 r;
  r[0] = pkbf(a[0], a[1]);
  r[1] = pkbf(a[2], a[3]);
  r[2] = pkbf(b[0], b[1]);
  r[3] = pkbf(b[2], b[3]);
  return __builtin_bit_cast(bf16x8, r);
}

// prep: W1 -> W1T [e][hcol][k96], W2 -> W2T [e][o16][k256]
#define PREP_T (184320 + 12288 + 8192 + 24576)
__global__ __launch_bounds__(256) void prep(const float* __restrict__ W1,
                                            const float* __restrict__ W2,
                                            unsigned short* __restrict__ W1T,
                                            unsigned short* __restrict__ W2T) {
  int tid = blockIdx.x * 256 + threadIdx.x;
  if (tid < 184320) {
    float v = W1[tid];
    int n = tid & 255, r = tid >> 8;
    int kp = r % 90, e = r / 90;
    W1T[(size_t)(e * NH + n) * 96 + kp] = f2bf(v);
    return;
  }
  tid -= 184320;
  if (tid < 12288) {
    int kp = 90 + tid % 6, q = tid / 6;
    int n = q & 255, e = q >> 8;
    W1T[(size_t)(e * NH + n) * 96 + kp] = 0;
    return;
  }
  tid -= 12288;
  if (tid < 8192) {
    float v = W2[tid];
    int o = tid & 3, k = (tid >> 2) & 255, e = tid >> 10;
    W2T[(size_t)(e * 16 + o) * NH + k] = f2bf(v);
    return;
  }
  tid -= 8192;
  if (tid < 24576) {
    int k = tid & 255, q = tid >> 8;
    int o = 4 + q % 12, e = q / 12;
    W2T[(size_t)(e * 16 + o) * NH + k] = 0;
  }
}

// Chunk-delayed layer-2 pipeline (R9 idea, R9's 2x LDS over-allocation fixed:
// sH is 16384 SHORTS = 32768 B, matching the index space gbase(max 3*4096)
// + region(2048) + offset(2047)).
__global__ __launch_bounds__(256, 3) void meganerf_main(
    const float* __restrict__ x, const float* __restrict__ cent,
    const float* __restrict__ b1, const float* __restrict__ b2,
    const unsigned short* __restrict__ W1T, const unsigned short* __restrict__ W2T,
    float* __restrict__ out) {
  __shared__ unsigned short sH[16384];     // 32768 B: per wave 2 regions x 4096 B
  __shared__ float sW[NE][64];             // 2048 B
  __shared__ float sB2[64][4];             // 1024 B  -> 35840 B total (4 blocks/CU)

  const int t    = threadIdx.x;
  const int lane = t & 63;
  const int wid  = t >> 6;
  const int l15  = lane & 15;
  const int l4   = lane >> 4;
  const int row0 = blockIdx.x * 64;
  const int gbase = wid * 4096;   // shorts; +2048 per region

  // ---- feat fragments (MFMA B operand), regs for all experts ----
  bf16x8 bfr[4][3];
#pragma unroll
  for (int nf = 0; nf < 4; ++nf) {
    const float* gr = x + (size_t)(row0 + 16 * nf + l15) * 93 + 3;
    f32x4 v0, v1;
    v0 = *(const f32x4a*)(gr + 8 * l4);
    v1 = *(const f32x4a*)(gr + 8 * l4 + 4);
    bfr[nf][0] = cvt8(v0, v1);
    v0 = *(const f32x4a*)(gr + 32 + 8 * l4);
    v1 = *(const f32x4a*)(gr + 36 + 8 * l4);
    bfr[nf][1] = cvt8(v0, v1);
    if (l4 < 3) {
      v0 = *(const f32x4a*)(gr + 64 + 8 * l4);
      v1 = *(const f32x4a*)(gr + 68 + 8 * l4);
    } else {
      f32x2 tl = *(const f32x2a*)(gr + 88);
      v0[0] = tl[0]; v0[1] = tl[1]; v0[2] = 0.f; v0[3] = 0.f;
      v1[0] = 0.f; v1[1] = 0.f; v1[2] = 0.f; v1[3] = 0.f;
    }
    bfr[nf][2] = cvt8(v0, v1);
  }

  // ---- per-point expert weights ----
  if (t < 64) {
    const float* gx = x + (size_t)(row0 + t) * 93;
    float px = gx[0], py = gx[1], pz = gx[2];
    float dist[NE], inv[NE];
    float mind = 3.4e38f;
#pragma unroll
    for (int e = 0; e < NE; ++e) {
      float dx = px - cent[e * 3 + 0];
      float dy = py - cent[e * 3 + 1];
      float dz = pz - cent[e * 3 + 2];
      float d2 = dx * dx + dy * dy + dz * dz;
      float d = sqrtf(fmaxf(d2, 0.f));
      dist[e] = d;
      inv[e] = 1.f / (d + 1e-8f);
      mind = fminf(mind, d);
    }
    float s = 0.f;
#pragma unroll
    for (int e = 0; e < NE; ++e) {
      if (dist[e] > 2.0f * mind) inv[e] = 0.f;
      s += inv[e];
    }
    float rs = 1.f / s;
    float bb[4] = {0.f, 0.f, 0.f, 0.f};
#pragma unroll
    for (int e = 0; e < NE; ++e) {
      float w = inv[e] * rs;
      sW[e][t] = w;
#pragma unroll
      for (int o = 0; o < 4; ++o) bb[o] += w * b2[e * 4 + o];
    }
#pragma unroll
    for (int o = 0; o < 4; ++o) sB2[t][o] = bb[o];
  }
  __syncthreads();   // covers sW, sB2

  f32x4 facc[4] = {{0.f, 0.f, 0.f, 0.f}, {0.f, 0.f, 0.f, 0.f},
                   {0.f, 0.f, 0.f, 0.f}, {0.f, 0.f, 0.f, 0.f}};
  float wv[4];

#pragma unroll 2
  for (int i = 0; i < 16; ++i) {
    const int e = i >> 1, c = i & 1;
    const int cur = i & 1, prev = cur ^ 1;
    const int colbase = 128 * c + 32 * wid;

    // ---- layer-2 for PREVIOUS chunk: issue reads early, compute later ----
    bf16x8 ah[4];
    bf16x8 bwp;
    if (i > 0) {
      const int ep = (i - 1) >> 1, cp = (i - 1) & 1;
#pragma unroll
      for (int rf = 0; rf < 4; ++rf)
        ah[rf] = *(const bf16x8*)&sH[gbase + prev * 2048 + (rf * 64 + lane) * 8];
      bwp = *(const bf16x8*)(W2T + (size_t)(ep * 16 + l15) * NH +
                             128 * cp + 32 * wid + 8 * l4);
    }

    // ---- this chunk's operands ----
    f32x4 b1v0 = *(const f32x4a*)(b1 + e * NH + colbase + 4 * l4);
    f32x4 b1v1 = *(const f32x4a*)(b1 + e * NH + colbase + 16 + 4 * l4);
    bf16x8 w1f[6];
    {
      const unsigned short* p =
          W1T + (size_t)(e * NH + colbase + l15) * 96 + 8 * l4;
#pragma unroll
      for (int mf = 0; mf < 2; ++mf)
#pragma unroll
        for (int ks = 0; ks < 3; ++ks)
          w1f[mf * 3 + ks] = *(const bf16x8*)(p + mf * (16 * 96) + 32 * ks);
    }
    if (c == 0) {
#pragma unroll
      for (int nf = 0; nf < 4; ++nf) wv[nf] = sW[e][16 * nf + l15];
    }

    // ---- layer 1, mf-sequential ----
#pragma unroll
    for (int mf = 0; mf < 2; ++mf) {
      const f32x4 b1v = (mf == 0) ? b1v0 : b1v1;
      f32x4 acc[4];
#pragma unroll
      for (int nf = 0; nf < 4; ++nf)
        acc[nf] = __builtin_amdgcn_mfma_f32_16x16x32_bf16(
            w1f[mf * 3 + 0], bfr[nf][0], b1v, 0, 0, 0);
#pragma unroll
      for (int ks = 1; ks < 3; ++ks)
#pragma unroll
        for (int nf = 0; nf < 4; ++nf)
          acc[nf] = __builtin_amdgcn_mfma_f32_16x16x32_bf16(
              w1f[mf * 3 + ks], bfr[nf][ks], acc[nf], 0, 0, 0);

      // layer-2 MFMAs for prev chunk between the two mf groups (reads long done)
      if (mf == 0 && i > 0) {
#pragma unroll
        for (int rf = 0; rf < 4; ++rf)
          facc[rf] = __builtin_amdgcn_mfma_f32_16x16x32_bf16(ah[rf], bwp, facc[rf], 0, 0, 0);
      }

      // epilogue: relu*w, pack, write region `cur`
#pragma unroll
      for (int nf = 0; nf < 4; ++nf) {
        const float w = wv[nf];
        f32x4 a = acc[nf];
        f32x2 p0, p1;
        p0[0] = a[0]; p0[1] = a[1];
        p1[0] = a[2]; p1[1] = a[3];
        const f32x2 z = {0.f, 0.f};
        p0 = __builtin_elementwise_max(p0, z) * w;
        p1 = __builtin_elementwise_max(p1, z) * w;
        u32x2 pk;
        pk[0] = pkbf(p0[0], p0[1]);
        pk[1] = pkbf(p1[0], p1[1]);
        *(u32x2*)&sH[gbase + cur * 2048 +
                     (nf * 64 + (l15 + 16 * (2 * mf + (l4 >> 1)))) * 8 +
                     4 * (l4 & 1)] = pk;
      }
    }
  }

  // ---- drain: layer-2 for chunk 15 (region 1, expert 7, c=1) ----
  {
    bf16x8 bwp = *(const bf16x8*)(W2T + (size_t)(7 * 16 + l15) * NH +
                                  128 + 32 * wid + 8 * l4);
#pragma unroll
    for (int rf = 0; rf < 4; ++rf) {
      bf16x8 ah = *(const bf16x8*)&sH[gbase + 2048 + (rf * 64 + lane) * 8];
      facc[rf] = __builtin_amdgcn_mfma_f32_16x16x32_bf16(ah, bwp, facc[rf], 0, 0, 0);
    }
  }

  // ---- cross-wave reduction (sOutP aliased onto sH) ----
  __syncthreads();
  float* sOutP = (float*)sH;
  if (l15 < 4) {
#pragma unroll
    for (int rf = 0; rf < 4; ++rf)
#pragma unroll
      for (int r = 0; r < 4; ++r)
        sOutP[(wid * 64 + 16 * rf + 4 * l4 + r) * 4 + l15] = facc[rf][r];
  }
  __syncthreads();
  {
    const int row = t >> 2, o = t & 3;
    float v = sB2[row][o] + sOutP[(0 * 64 + row) * 4 + o] + sOutP[(1 * 64 + row) * 4 + o] +
              sOutP[(2 * 64 + row) * 4 + o] + sOutP[(3 * 64 + row) * 4 + o];
    out[row0 * 4 + t] = v;
  }
}

extern "C" void kernel_launch(void* const* d_in, const int* in_sizes, int n_in,
                              void* d_out, int out_size, void* d_ws, size_t ws_size,
                              hipStream_t stream) {
  const float* x    = (const float*)d_in[0];
  const float* cent = (const float*)d_in[1];
  const float* W1   = (const float*)d_in[2];
  const float* b1   = (const float*)d_in[3];
  const float* W2   = (const float*)d_in[4];
  const float* b2   = (const float*)d_in[5];
  float* out = (float*)d_out;

  unsigned short* W1T = (unsigned short*)d_ws;   // 393216 B
  unsigned short* W2T = W1T + NE * NH * 96;      // 65536 B

  prep<<<(PREP_T + 255) / 256, 256, 0, stream>>>(W1, W2, W1T, W2T);
  meganerf_main<<<NPTS / 64, 256, 0, stream>>>(x, cent, b1, b2, W1T, W2T, out);
}